// Round 1
// baseline (460.039 us; speedup 1.0000x reference)
//
#include <hip/hip_runtime.h>
#include <hip/hip_bf16.h>
#include <hip/hip_fp16.h>

#define E4M3_MAX 240.0f

typedef __attribute__((ext_vector_type(8))) __bf16 bf16x8;
typedef __attribute__((ext_vector_type(4))) float f32x4;

__device__ __forceinline__ void gload_lds16(const void* g, void* l) {
  __builtin_amdgcn_global_load_lds(
      (const __attribute__((address_space(1))) void*)g,
      (__attribute__((address_space(3))) void*)l,
      16, 0, 0);
}

// ---------------- amax over |weight| ----------------
__global__ void amax_abs_kernel(const float* __restrict__ w, int n4,
                                unsigned* __restrict__ amax_bits) {
  float m = 0.0f;
  const float4* w4 = (const float4*)w;
  int stride = gridDim.x * blockDim.x;
  for (int i = blockIdx.x * blockDim.x + threadIdx.x; i < n4; i += stride) {
    float4 v = w4[i];
    m = fmaxf(m, fmaxf(fmaxf(fabsf(v.x), fabsf(v.y)),
                       fmaxf(fabsf(v.z), fabsf(v.w))));
  }
  // wave-64 reduce
  for (int off = 32; off > 0; off >>= 1)
    m = fmaxf(m, __shfl_down(m, off, 64));
  __shared__ float smax[4];
  int l = threadIdx.x & 63, wv = threadIdx.x >> 6;
  if (l == 0) smax[wv] = m;
  __syncthreads();
  if (threadIdx.x == 0) {
    float bm = fmaxf(fmaxf(smax[0], smax[1]), fmaxf(smax[2], smax[3]));
    atomicMax(amax_bits, __float_as_uint(bm));
  }
}

// ---------------- quantize weight -> bf16 qw ----------------
__global__ void quant_weight_kernel(const float* __restrict__ w,
                                    const unsigned* __restrict__ amax_bits,
                                    unsigned short* __restrict__ qw, int n4) {
  float amax = __uint_as_float(*amax_bits);
  float scale = fmaxf(amax / E4M3_MAX, 1e-10f);
  const float4* w4 = (const float4*)w;
  ushort4* q4 = (ushort4*)qw;
  int stride = gridDim.x * blockDim.x;
  for (int i = blockIdx.x * blockDim.x + threadIdx.x; i < n4; i += stride) {
    float4 v = w4[i];
    float r[4] = {v.x, v.y, v.z, v.w};
    unsigned short o[4];
#pragma unroll
    for (int j = 0; j < 4; ++j) {
      float s = fminf(fmaxf(r[j] / scale, -E4M3_MAX), E4M3_MAX);
      s = __half2float(__float2half(s));            // fp16 round-trip (RNE)
      float q = rintf(s * 8.0f) * 0.125f;           // mantissa grid, half-to-even
      q = fminf(fmaxf(q, -E4M3_MAX), E4M3_MAX);
      __hip_bfloat16 h = __float2bfloat16(q * scale);
      o[j] = *(unsigned short*)&h;
    }
    ushort4 ov = {o[0], o[1], o[2], o[3]};
    q4[i] = ov;
  }
}

// ---------------- convert x fp32 -> bf16 ----------------
__global__ void cvt_bf16_kernel(const float* __restrict__ x,
                                unsigned short* __restrict__ xb, int n4) {
  const float4* x4 = (const float4*)x;
  ushort4* o4 = (ushort4*)xb;
  int stride = gridDim.x * blockDim.x;
  for (int i = blockIdx.x * blockDim.x + threadIdx.x; i < n4; i += stride) {
    float4 v = x4[i];
    __hip_bfloat16 h0 = __float2bfloat16(v.x);
    __hip_bfloat16 h1 = __float2bfloat16(v.y);
    __hip_bfloat16 h2 = __float2bfloat16(v.z);
    __hip_bfloat16 h3 = __float2bfloat16(v.w);
    ushort4 o = {*(unsigned short*)&h0, *(unsigned short*)&h1,
                 *(unsigned short*)&h2, *(unsigned short*)&h3};
    o4[i] = o;
  }
}

// ---------------- bf16 GEMM (m97 structure): C = A * Bt^T + bias ----------------
// A: [M][K] bf16, Bt: [N][K] bf16, C: [M][N] fp32
__global__ __launch_bounds__(256) void gemm_bf16_bias(
    const unsigned short* __restrict__ A, const unsigned short* __restrict__ Bt,
    const float* __restrict__ bias, float* __restrict__ C,
    int M, int N, int K) {
  constexpr int BM = 128, BN = 128, BK = 32;
  __shared__ __align__(16) unsigned short As[BM * BK];
  __shared__ __align__(16) unsigned short Bs[BN * BK];

  const int nbn = N / BN;
  const int nwg = (M / BM) * nbn;
  // bijective XCD swizzle (8 XCDs)
  int bid = blockIdx.x;
  int q8 = nwg >> 3, r8 = nwg & 7;
  int xcd = bid & 7, idx = bid >> 3;
  int swz = (xcd < r8) ? (xcd * (q8 + 1) + idx)
                       : (r8 * (q8 + 1) + (xcd - r8) * q8 + idx);
  int bm = swz / nbn, bn = swz % nbn;

  int t = threadIdx.x;
  int w = t >> 6, l = t & 63;
  int wr = (w >> 1) * 64, wc = (w & 1) * 64;  // wave sub-tile origin (64x64)
  int lr = l & 15, lk = l >> 4;               // fragment row, k-group

  const unsigned short* Ab = A + (size_t)bm * BM * K;
  const unsigned short* Bb = Bt + (size_t)bn * BN * K;

  f32x4 acc[4][4] = {};

  for (int kk = 0; kk < K; kk += BK) {
#pragma unroll
    for (int q = 0; q < 2; ++q) {
      int s = q * 256 + t;              // 16B slot; row = s>>2, kgrp = s&3
      int row = s >> 2, g = s & 3;
      gload_lds16(Ab + (size_t)row * K + kk + g * 8,
                  As + (size_t)(q * 256 + w * 64) * 8);
      gload_lds16(Bb + (size_t)row * K + kk + g * 8,
                  Bs + (size_t)(q * 256 + w * 64) * 8);
    }
    __syncthreads();   // drains vmcnt(0) for global_load_lds

    bf16x8 af[4], bfr[4];
#pragma unroll
    for (int i = 0; i < 4; ++i)
      af[i] = *(const bf16x8*)&As[(wr + i * 16 + lr) * BK + lk * 8];
#pragma unroll
    for (int j = 0; j < 4; ++j)
      bfr[j] = *(const bf16x8*)&Bs[(wc + j * 16 + lr) * BK + lk * 8];

#pragma unroll
    for (int i = 0; i < 4; ++i)
#pragma unroll
      for (int j = 0; j < 4; ++j)
        acc[i][j] = __builtin_amdgcn_mfma_f32_16x16x32_bf16(
            af[i], bfr[j], acc[i][j], 0, 0, 0);

    __syncthreads();   // protect LDS before next-tile overwrite
  }

  // epilogue: D layout col = lane&15, row = (lane>>4)*4 + reg (m89-verified)
  float* Cb = C + (size_t)(bm * BM) * N + bn * BN;
#pragma unroll
  for (int j = 0; j < 4; ++j) {
    int n = wc + j * 16 + lr;
    float bv = bias[bn * BN + n];
#pragma unroll
    for (int i = 0; i < 4; ++i) {
      int m0 = wr + i * 16 + lk * 4;
#pragma unroll
      for (int r = 0; r < 4; ++r)
        Cb[(size_t)(m0 + r) * N + n] = acc[i][j][r] + bv;
    }
  }
}

extern "C" void kernel_launch(void* const* d_in, const int* in_sizes, int n_in,
                              void* d_out, int out_size, void* d_ws, size_t ws_size,
                              hipStream_t stream) {
  const float* x = (const float*)d_in[0];     // [4,2048,4096] fp32
  const float* wt = (const float*)d_in[1];    // [4096,4096] fp32
  const float* bias = (const float*)d_in[2];  // [4096] fp32
  float* out = (float*)d_out;                 // [4,2048,4096] fp32

  const int DIN = 4096, DOUT = 4096;
  const int M = in_sizes[0] / DIN;            // 8192
  const int NW = in_sizes[1];                 // 16777216

  char* ws = (char*)d_ws;
  unsigned* amax_bits = (unsigned*)ws;
  unsigned short* qw = (unsigned short*)(ws + 256);                    // bf16 [DOUT][DIN]
  unsigned short* xb = (unsigned short*)(ws + 256 + (size_t)NW * 2);   // bf16 [M][DIN]

  hipMemsetAsync(amax_bits, 0, 4, stream);
  hipLaunchKernelGGL(amax_abs_kernel, dim3(1024), dim3(256), 0, stream,
                     wt, NW / 4, amax_bits);
  hipLaunchKernelGGL(quant_weight_kernel, dim3(2048), dim3(256), 0, stream,
                     wt, amax_bits, qw, NW / 4);
  hipLaunchKernelGGL(cvt_bf16_kernel, dim3(2048), dim3(256), 0, stream,
                     x, xb, (M * DIN) / 4);

  int nwg = (M / 128) * (DOUT / 128);         // 64*32 = 2048
  hipLaunchKernelGGL(gemm_bf16_bias, dim3(nwg), dim3(256), 0, stream,
                     xb, qw, bias, out, M, DOUT, DIN);
}

// Round 2
// 329.423 us; speedup vs baseline: 1.3965x; 1.3965x over previous
//
#include <hip/hip_runtime.h>
#include <hip/hip_bf16.h>
#include <hip/hip_fp16.h>

#define E4M3_MAX 240.0f

typedef __attribute__((ext_vector_type(8))) __bf16 bf16x8;
typedef __attribute__((ext_vector_type(4))) float f32x4;
typedef unsigned short ushort_t;

__device__ __forceinline__ void gload_lds16(const void* g, void* l) {
  __builtin_amdgcn_global_load_lds(
      (const __attribute__((address_space(1))) void*)g,
      (__attribute__((address_space(3))) void*)l,
      16, 0, 0);
}

// ---------------- amax over |weight| ----------------
__global__ void amax_abs_kernel(const float* __restrict__ w, int n4,
                                unsigned* __restrict__ amax_bits) {
  float m = 0.0f;
  const float4* w4 = (const float4*)w;
  int stride = gridDim.x * blockDim.x;
  for (int i = blockIdx.x * blockDim.x + threadIdx.x; i < n4; i += stride) {
    float4 v = w4[i];
    m = fmaxf(m, fmaxf(fmaxf(fabsf(v.x), fabsf(v.y)),
                       fmaxf(fabsf(v.z), fabsf(v.w))));
  }
  for (int off = 32; off > 0; off >>= 1)
    m = fmaxf(m, __shfl_down(m, off, 64));
  __shared__ float smax[4];
  int l = threadIdx.x & 63, wv = threadIdx.x >> 6;
  if (l == 0) smax[wv] = m;
  __syncthreads();
  if (threadIdx.x == 0) {
    float bm = fmaxf(fmaxf(smax[0], smax[1]), fmaxf(smax[2], smax[3]));
    atomicMax(amax_bits, __float_as_uint(bm));
  }
}

// ---------------- quantize weight -> bf16 qw ----------------
__global__ void quant_weight_kernel(const float* __restrict__ w,
                                    const unsigned* __restrict__ amax_bits,
                                    ushort_t* __restrict__ qw, int n4) {
  float amax = __uint_as_float(*amax_bits);
  float scale = fmaxf(amax / E4M3_MAX, 1e-10f);
  const float4* w4 = (const float4*)w;
  ushort4* q4 = (ushort4*)qw;
  int stride = gridDim.x * blockDim.x;
  for (int i = blockIdx.x * blockDim.x + threadIdx.x; i < n4; i += stride) {
    float4 v = w4[i];
    float r[4] = {v.x, v.y, v.z, v.w};
    ushort_t o[4];
#pragma unroll
    for (int j = 0; j < 4; ++j) {
      float s = fminf(fmaxf(r[j] / scale, -E4M3_MAX), E4M3_MAX);
      s = __half2float(__float2half(s));   // fp16 round-trip (RNE)
      float q = rintf(s * 8.0f) * 0.125f;  // mantissa grid, half-to-even
      q = fminf(fmaxf(q, -E4M3_MAX), E4M3_MAX);
      __hip_bfloat16 h = __float2bfloat16(q * scale);
      o[j] = *(ushort_t*)&h;
    }
    ushort4 ov = {o[0], o[1], o[2], o[3]};
    q4[i] = ov;
  }
}

// ---------------- convert x fp32 -> bf16 ----------------
__global__ void cvt_bf16_kernel(const float* __restrict__ x,
                                ushort_t* __restrict__ xb, int n4) {
  const float4* x4 = (const float4*)x;
  ushort4* o4 = (ushort4*)xb;
  int stride = gridDim.x * blockDim.x;
  for (int i = blockIdx.x * blockDim.x + threadIdx.x; i < n4; i += stride) {
    float4 v = x4[i];
    __hip_bfloat16 h0 = __float2bfloat16(v.x);
    __hip_bfloat16 h1 = __float2bfloat16(v.y);
    __hip_bfloat16 h2 = __float2bfloat16(v.z);
    __hip_bfloat16 h3 = __float2bfloat16(v.w);
    ushort4 o = {*(ushort_t*)&h0, *(ushort_t*)&h1,
                 *(ushort_t*)&h2, *(ushort_t*)&h3};
    o4[i] = o;
  }
}

// ============ 256x256 8-phase bf16 GEMM: C = A * Bt^T + bias ============
// A: [M=8192][K=4096] bf16, Bt: [N=4096][K=4096] bf16, C fp32.
// 8 waves (2M x 4N), BK=64, dbuf LDS 128 KiB, counted vmcnt, XOR-swizzled LDS.

#define BAR() do { asm volatile("" ::: "memory"); \
                   __builtin_amdgcn_s_barrier(); \
                   asm volatile("" ::: "memory"); } while (0)
#define LGKM0() asm volatile("s_waitcnt lgkmcnt(0)" ::: "memory")
#define LGKM8() asm volatile("s_waitcnt lgkmcnt(8)" ::: "memory")
#define VMC(N)  asm volatile("s_waitcnt vmcnt(" #N ")" ::: "memory")

__global__ __launch_bounds__(512, 2) void gemm256_8ph(
    const ushort_t* __restrict__ A, const ushort_t* __restrict__ Bt,
    const float* __restrict__ bias, float* __restrict__ C) {
  constexpr int K = 4096, N = 4096;
  // LDS: [buf][half][128 rows * 64 cols] per matrix = 2*2*8192*2B*2 = 128 KiB
  __shared__ __align__(16) ushort_t As[2][2][8192];
  __shared__ __align__(16) ushort_t Bs[2][2][8192];

  const int tid = threadIdx.x;
  const int wid = tid >> 6, lane = tid & 63;
  const int wm = wid >> 2, wn = wid & 3;     // 2 x 4 wave grid
  const int lk = lane >> 4, lr = lane & 15;

  // XCD swizzle: nwg=512, 512%8==0 -> simple bijective form
  int bid = blockIdx.x;
  int swz = (bid & 7) * 64 + (bid >> 3);
  int bm = swz >> 4, bn = swz & 15;          // nbn = 16

  const ushort_t* Ab = A + (size_t)bm * 256 * K;
  const ushort_t* Bb = Bt + (size_t)bn * 256 * K;

  // staging offsets: thread tid, load q: slot s = q*512+tid; row=s>>3,
  // 16B-granule c = (s&7) ^ (row&7)  (pre-swizzled global source)
  int offG[2];
#pragma unroll
  for (int q = 0; q < 2; ++q) {
    int s = q * 512 + tid;
    int row = s >> 3;
    int c = (s & 7) ^ (row & 7);
    offG[q] = row * K + c * 8;
  }

#define STAGE_A(buf, half, kt)                                            \
  do { _Pragma("unroll") for (int q = 0; q < 2; ++q)                      \
    gload_lds16(Ab + (size_t)(half) * 128 * K + (kt) * 64 + offG[q],      \
                &As[buf][half][(q * 512 + wid * 64) * 8]); } while (0)
#define STAGE_B(buf, half, kt)                                            \
  do { _Pragma("unroll") for (int q = 0; q < 2; ++q)                      \
    gload_lds16(Bb + (size_t)(half) * 128 * K + (kt) * 64 + offG[q],      \
                &Bs[buf][half][(q * 512 + wid * 64) * 8]); } while (0)

  // ds_read addressing (swizzled): granule (ks*4+lk) ^ (lr&7)
  const int abase = lr * 64;
  const int bbase = (wn & 1) * 4096 + lr * 64;
  const int bhalf = wn >> 1;
  const int xk0 = ((lk) ^ (lr & 7)) * 8;
  const int xk1 = ((4 + lk) ^ (lr & 7)) * 8;

  bf16x8 afr[8][2], bfr[4][2];
  f32x4 acc[8][4] = {};

#define RD_B(buf)                                                         \
  do { _Pragma("unroll") for (int fj = 0; fj < 4; ++fj) {                 \
    bfr[fj][0] = *(const bf16x8*)&Bs[buf][bhalf][bbase + fj * 1024 + xk0];\
    bfr[fj][1] = *(const bf16x8*)&Bs[buf][bhalf][bbase + fj * 1024 + xk1];\
  } } while (0)
#define RD_A(buf, F0, F1)                                                 \
  do { _Pragma("unroll") for (int fi = F0; fi < F1; ++fi) {               \
    afr[fi][0] = *(const bf16x8*)&As[buf][wm][abase + fi * 1024 + xk0];   \
    afr[fi][1] = *(const bf16x8*)&As[buf][wm][abase + fi * 1024 + xk1];   \
  } } while (0)
#define MMA_Q(q)                                                          \
  do { __builtin_amdgcn_s_setprio(1);                                     \
    _Pragma("unroll") for (int fi = (q)*2; fi < (q)*2 + 2; ++fi)          \
      _Pragma("unroll") for (int fj = 0; fj < 4; ++fj) {                  \
        acc[fi][fj] = __builtin_amdgcn_mfma_f32_16x16x32_bf16(            \
            afr[fi][0], bfr[fj][0], acc[fi][fj], 0, 0, 0);                \
        acc[fi][fj] = __builtin_amdgcn_mfma_f32_16x16x32_bf16(            \
            afr[fi][1], bfr[fj][1], acc[fi][fj], 0, 0, 0);                \
      }                                                                   \
    __builtin_amdgcn_s_setprio(0); } while (0)

  // ---- prologue: tile0 full + tile1 A-halves in flight ----
  STAGE_A(0, 0, 0); STAGE_A(0, 1, 0);
  STAGE_B(0, 0, 0); STAGE_B(0, 1, 0);
  STAGE_A(1, 0, 1); STAGE_A(1, 1, 1);
  VMC(4);   // tile0 retired; tile1 A0,A1 stay in flight
  BAR();

  // ---- main loop: 2 K-tiles / iteration, 8 phases ----
  for (int t = 0; t < 62; t += 2) {
    // phase 1: reads tile t (buf0): B all + A quad0; stage t+1 B0
    RD_B(0); RD_A(0, 0, 2);
    STAGE_B(1, 0, t + 1);
    LGKM8(); BAR(); LGKM0(); MMA_Q(0); BAR();
    // phase 2: A quads 1-3; stage t+1 B1
    RD_A(0, 2, 8);
    STAGE_B(1, 1, t + 1);
    LGKM8(); BAR(); LGKM0(); MMA_Q(1); BAR();
    // phase 3: stage t+2 A0 (buf0 reads completed at Y2)
    STAGE_A(0, 0, t + 2);
    BAR(); MMA_Q(2); BAR();
    // phase 4: stage t+2 A1; counted vmcnt retires tile t+1 fully
    STAGE_A(0, 1, t + 2);
    BAR(); MMA_Q(3); VMC(4); BAR();
    // phase 5: reads tile t+1 (buf1); stage t+2 B0
    RD_B(1); RD_A(1, 0, 2);
    STAGE_B(0, 0, t + 2);
    LGKM8(); BAR(); LGKM0(); MMA_Q(0); BAR();
    // phase 6
    RD_A(1, 2, 8);
    STAGE_B(0, 1, t + 2);
    LGKM8(); BAR(); LGKM0(); MMA_Q(1); BAR();
    // phase 7: stage t+3 A0
    STAGE_A(1, 0, t + 3);
    BAR(); MMA_Q(2); BAR();
    // phase 8: stage t+3 A1; counted vmcnt retires tile t+2 fully
    STAGE_A(1, 1, t + 3);
    BAR(); MMA_Q(3); VMC(4); BAR();
  }

  // ---- epilogue: tiles 62 (buf0) and 63 (buf1) ----
  RD_B(0); RD_A(0, 0, 2);
  STAGE_B(1, 0, 63);
  LGKM8(); BAR(); LGKM0(); MMA_Q(0); BAR();
  RD_A(0, 2, 8);
  STAGE_B(1, 1, 63);
  LGKM8(); BAR(); LGKM0(); MMA_Q(1); BAR();
  MMA_Q(2); MMA_Q(3);
  VMC(0);   // tile 63 fully in LDS
  BAR();
  RD_B(1); RD_A(1, 0, 8);
  LGKM0();
  MMA_Q(0); MMA_Q(1); MMA_Q(2); MMA_Q(3);

  // ---- C write + bias (D: col = lane&15 -> n, row = lk*4+reg -> m) ----
  float* Cb = C + (size_t)(bm * 256 + wm * 128) * N + bn * 256 + wn * 64;
#pragma unroll
  for (int fj = 0; fj < 4; ++fj) {
    int n = fj * 16 + lr;
    float bv = bias[bn * 256 + wn * 64 + n];
#pragma unroll
    for (int fi = 0; fi < 8; ++fi) {
      int m0 = fi * 16 + lk * 4;
#pragma unroll
      for (int r = 0; r < 4; ++r)
        Cb[(size_t)(m0 + r) * N + n] = acc[fi][fj][r] + bv;
    }
  }
}

extern "C" void kernel_launch(void* const* d_in, const int* in_sizes, int n_in,
                              void* d_out, int out_size, void* d_ws, size_t ws_size,
                              hipStream_t stream) {
  const float* x = (const float*)d_in[0];     // [4,2048,4096] fp32
  const float* wt = (const float*)d_in[1];    // [4096,4096] fp32
  const float* bias = (const float*)d_in[2];  // [4096] fp32
  float* out = (float*)d_out;                 // [4,2048,4096] fp32

  const int DIN = 4096;
  const int NW = in_sizes[1];                 // 16777216
  const int M = in_sizes[0] / DIN;            // 8192

  char* ws = (char*)d_ws;
  unsigned* amax_bits = (unsigned*)ws;
  ushort_t* qw = (ushort_t*)(ws + 256);                    // bf16 [4096][4096]
  ushort_t* xb = (ushort_t*)(ws + 256 + (size_t)NW * 2);   // bf16 [8192][4096]

  hipMemsetAsync(amax_bits, 0, 4, stream);
  hipLaunchKernelGGL(amax_abs_kernel, dim3(1024), dim3(256), 0, stream,
                     wt, NW / 4, amax_bits);
  hipLaunchKernelGGL(quant_weight_kernel, dim3(2048), dim3(256), 0, stream,
                     wt, amax_bits, qw, NW / 4);
  hipLaunchKernelGGL(cvt_bf16_kernel, dim3(2048), dim3(256), 0, stream,
                     x, xb, (M * DIN) / 4);

  // 32 x 16 = 512 workgroups of 512 threads
  hipLaunchKernelGGL(gemm256_8ph, dim3(512), dim3(512), 0, stream,
                     xb, qw, bias, out);
}